// Round 1
// baseline (217.178 us; speedup 1.0000x reference)
//
#include <hip/hip_runtime.h>

// Trilinear (3-D multilinear) interpolated table lookup.
// unList: [B, 3] f32 normalized coords in [0,1]
// table : [128, 128, 128, 8] f32
// out   : [B, 8] f32
//
// Per point: scaled = clip(u,0,1)*(dim-1); i0 = clip(floor(scaled),0,dim-2);
// frac = scaled - i0; out[c] = sum over 8 corners w * table[corner][c].
// The two z-corners are contiguous (16 floats = 64 B), so we do 4 gather
// groups of 4x float4 each.

#define DIM 128
#define CH 8

__global__ __launch_bounds__(256) void pseudogrid3d_kernel(
    const float* __restrict__ un,
    const float* __restrict__ table,
    float* __restrict__ out,
    int batch)
{
    int b = blockIdx.x * blockDim.x + threadIdx.x;
    if (b >= batch) return;

    // load 3 coords
    float ux = un[3 * b + 0];
    float uy = un[3 * b + 1];
    float uz = un[3 * b + 2];

    const float dmax = (float)(DIM - 1);   // 127
    const float imax = (float)(DIM - 2);   // 126

    float sx = fminf(fmaxf(ux, 0.0f), 1.0f) * dmax;
    float sy = fminf(fmaxf(uy, 0.0f), 1.0f) * dmax;
    float sz = fminf(fmaxf(uz, 0.0f), 1.0f) * dmax;

    float fx0 = fminf(fmaxf(floorf(sx), 0.0f), imax);
    float fy0 = fminf(fmaxf(floorf(sy), 0.0f), imax);
    float fz0 = fminf(fmaxf(floorf(sz), 0.0f), imax);

    int x0 = (int)fx0;
    int y0 = (int)fy0;
    int z0 = (int)fz0;

    float fx = sx - fx0;
    float fy = sy - fy0;
    float fz = sz - fz0;

    float wx[2] = {1.0f - fx, fx};
    float wy[2] = {1.0f - fy, fy};
    float wz0 = 1.0f - fz, wz1 = fz;

    float acc[CH];
#pragma unroll
    for (int c = 0; c < CH; ++c) acc[c] = 0.0f;

    // base row for (x0, y0, z0); each grid cell is CH floats (32 B aligned)
#pragma unroll
    for (int bx = 0; bx < 2; ++bx) {
#pragma unroll
        for (int by = 0; by < 2; ++by) {
            const float* p = table +
                ((size_t)((x0 + bx) * DIM + (y0 + by)) * DIM + z0) * CH;
            float wxy = wx[bx] * wy[by];
            float w0 = wxy * wz0;
            float w1 = wxy * wz1;
            // 16 contiguous floats: z-corner 0 (8) then z-corner 1 (8)
            float4 a0 = *reinterpret_cast<const float4*>(p + 0);
            float4 a1 = *reinterpret_cast<const float4*>(p + 4);
            float4 b0 = *reinterpret_cast<const float4*>(p + 8);
            float4 b1 = *reinterpret_cast<const float4*>(p + 12);
            acc[0] += w0 * a0.x + w1 * b0.x;
            acc[1] += w0 * a0.y + w1 * b0.y;
            acc[2] += w0 * a0.z + w1 * b0.z;
            acc[3] += w0 * a0.w + w1 * b0.w;
            acc[4] += w0 * a1.x + w1 * b1.x;
            acc[5] += w0 * a1.y + w1 * b1.y;
            acc[6] += w0 * a1.z + w1 * b1.z;
            acc[7] += w0 * a1.w + w1 * b1.w;
        }
    }

    float4* o = reinterpret_cast<float4*>(out + (size_t)b * CH);
    o[0] = make_float4(acc[0], acc[1], acc[2], acc[3]);
    o[1] = make_float4(acc[4], acc[5], acc[6], acc[7]);
}

extern "C" void kernel_launch(void* const* d_in, const int* in_sizes, int n_in,
                              void* d_out, int out_size, void* d_ws, size_t ws_size,
                              hipStream_t stream) {
    const float* un    = (const float*)d_in[0];   // [B, 3]
    const float* table = (const float*)d_in[1];   // [128,128,128,8]
    float* out         = (float*)d_out;           // [B, 8]

    int batch = in_sizes[0] / 3;
    int block = 256;
    int grid = (batch + block - 1) / block;
    pseudogrid3d_kernel<<<grid, block, 0, stream>>>(un, table, out, batch);
}

// Round 2
// 158.334 us; speedup vs baseline: 1.3717x; 1.3717x over previous
//
#include <hip/hip_runtime.h>

// Trilinear table lookup with spatial pre-sort for L2 locality.
//
// unList: [B, 3] f32 coords in [0,1];  table: [128,128,128,8] f32;  out: [B,8] f32
//
// Random points over a 64 MB table blow out per-XCD L2 (4 MiB). We counting-sort
// points by x-plane (128 bins), then process in sorted order with an XCD-aware
// block swizzle so each XCD streams a contiguous table slab (working window
// ~2-3 planes = ~1.5 MB, L2-resident).

#define DIM 128
#define CH 8
#define BINS 128
#define CHUNK 4096   // points per scatter block
#define PPT 16       // CHUNK / 256

// ws layout (byte offsets):
//   [0,    512)  hist   (u32 x 128)
//   [512, 1024)  base   (u32 x 128)
//   [1024,1536)  cursor (u32 x 128)
//   [4096, 4096 + B*16)  sorted records (float4: x,y,z, bits(orig_idx))
#define REC_OFF 4096

__device__ __forceinline__ int key_of(float ux) {
    float sx = fminf(fmaxf(ux, 0.0f), 1.0f) * 127.0f;
    float fx0 = fminf(floorf(sx), 126.0f);
    return (int)fx0;   // 0..126
}

__global__ __launch_bounds__(256) void k_hist(const float* __restrict__ un,
                                              unsigned* __restrict__ hist, int batch) {
    __shared__ unsigned lh[BINS];
    for (int i = threadIdx.x; i < BINS; i += blockDim.x) lh[i] = 0;
    __syncthreads();
    int stride = gridDim.x * blockDim.x;
    for (int i = blockIdx.x * blockDim.x + threadIdx.x; i < batch; i += stride)
        atomicAdd(&lh[key_of(un[3 * i])], 1u);
    __syncthreads();
    for (int i = threadIdx.x; i < BINS; i += blockDim.x)
        if (lh[i]) atomicAdd(&hist[i], lh[i]);
}

__global__ void k_scan(const unsigned* __restrict__ hist,
                       unsigned* __restrict__ base, unsigned* __restrict__ cursor) {
    __shared__ unsigned lh[BINS];
    __shared__ unsigned lb[BINS];
    int t = threadIdx.x;
    if (t < BINS) lh[t] = hist[t];
    __syncthreads();
    if (t == 0) {
        unsigned acc = 0;
        for (int i = 0; i < BINS; ++i) { lb[i] = acc; acc += lh[i]; }
    }
    __syncthreads();
    if (t < BINS) { base[t] = lb[t]; cursor[t] = lb[t]; }
}

__global__ __launch_bounds__(256) void k_scatter(const float* __restrict__ un,
                                                 unsigned* __restrict__ cursor,
                                                 float4* __restrict__ rec, int batch) {
    __shared__ unsigned lh[BINS];
    __shared__ unsigned lbase[BINS];
    int t = threadIdx.x;
    for (int i = t; i < BINS; i += blockDim.x) lh[i] = 0;
    __syncthreads();
    int start = blockIdx.x * CHUNK;
    unsigned kr[PPT];
#pragma unroll
    for (int j = 0; j < PPT; ++j) {
        int i = start + j * 256 + t;
        if (i < batch) {
            int k = key_of(un[3 * i]);
            unsigned r = atomicAdd(&lh[k], 1u);      // intra-block rank
            kr[j] = (unsigned)k | (r << 8);
        } else kr[j] = 0xFFFFFFFFu;
    }
    __syncthreads();
    for (int i = t; i < BINS; i += blockDim.x)
        lbase[i] = lh[i] ? atomicAdd(&cursor[i], lh[i]) : 0u;
    __syncthreads();
#pragma unroll
    for (int j = 0; j < PPT; ++j) {
        int i = start + j * 256 + t;
        if (i < batch) {
            unsigned k = kr[j] & 0xFFu, r = kr[j] >> 8;
            float ux = un[3 * i], uy = un[3 * i + 1], uz = un[3 * i + 2];  // L1/L2-hot
            rec[lbase[k] + r] = make_float4(ux, uy, uz, __uint_as_float((unsigned)i));
        }
    }
}

__device__ __forceinline__ void trilerp_store(float ux, float uy, float uz,
                                              const float* __restrict__ table,
                                              float* __restrict__ o8) {
    const float dmax = 127.0f, imax = 126.0f;
    float sx = fminf(fmaxf(ux, 0.0f), 1.0f) * dmax;
    float sy = fminf(fmaxf(uy, 0.0f), 1.0f) * dmax;
    float sz = fminf(fmaxf(uz, 0.0f), 1.0f) * dmax;
    float fx0 = fminf(fmaxf(floorf(sx), 0.0f), imax);
    float fy0 = fminf(fmaxf(floorf(sy), 0.0f), imax);
    float fz0 = fminf(fmaxf(floorf(sz), 0.0f), imax);
    int x0 = (int)fx0, y0 = (int)fy0, z0 = (int)fz0;
    float fx = sx - fx0, fy = sy - fy0, fz = sz - fz0;
    float wx[2] = {1.0f - fx, fx};
    float wy[2] = {1.0f - fy, fy};
    float wz0 = 1.0f - fz, wz1 = fz;

    float acc[CH];
#pragma unroll
    for (int c = 0; c < CH; ++c) acc[c] = 0.0f;
#pragma unroll
    for (int bx = 0; bx < 2; ++bx) {
#pragma unroll
        for (int by = 0; by < 2; ++by) {
            const float* p = table + ((size_t)((x0 + bx) * DIM + (y0 + by)) * DIM + z0) * CH;
            float wxy = wx[bx] * wy[by];
            float w0 = wxy * wz0, w1 = wxy * wz1;
            float4 a0 = *reinterpret_cast<const float4*>(p + 0);
            float4 a1 = *reinterpret_cast<const float4*>(p + 4);
            float4 b0 = *reinterpret_cast<const float4*>(p + 8);
            float4 b1 = *reinterpret_cast<const float4*>(p + 12);
            acc[0] += w0 * a0.x + w1 * b0.x;
            acc[1] += w0 * a0.y + w1 * b0.y;
            acc[2] += w0 * a0.z + w1 * b0.z;
            acc[3] += w0 * a0.w + w1 * b0.w;
            acc[4] += w0 * a1.x + w1 * b1.x;
            acc[5] += w0 * a1.y + w1 * b1.y;
            acc[6] += w0 * a1.z + w1 * b1.z;
            acc[7] += w0 * a1.w + w1 * b1.w;
        }
    }
    float4* o = reinterpret_cast<float4*>(o8);
    o[0] = make_float4(acc[0], acc[1], acc[2], acc[3]);
    o[1] = make_float4(acc[4], acc[5], acc[6], acc[7]);
}

__global__ __launch_bounds__(256) void k_main(const float4* __restrict__ rec,
                                              const float* __restrict__ table,
                                              float* __restrict__ out, int batch) {
    // XCD-aware swizzle: physical block p -> logical lb so XCD (p%8) gets a
    // contiguous sorted range (gridDim.x % 8 == 0 guaranteed by launch).
    int per = gridDim.x >> 3;
    int p = blockIdx.x;
    int lb = (p & 7) * per + (p >> 3);
    int i = lb * 256 + (int)threadIdx.x;
    if (i >= batch) return;
    float4 r = rec[i];
    unsigned orig = __float_as_uint(r.w);
    trilerp_store(r.x, r.y, r.z, table, out + (size_t)orig * CH);
}

// Fallback (no workspace): direct gather, round-1 kernel.
__global__ __launch_bounds__(256) void k_naive(const float* __restrict__ un,
                                               const float* __restrict__ table,
                                               float* __restrict__ out, int batch) {
    int b = blockIdx.x * blockDim.x + threadIdx.x;
    if (b >= batch) return;
    trilerp_store(un[3 * b], un[3 * b + 1], un[3 * b + 2], table, out + (size_t)b * CH);
}

extern "C" void kernel_launch(void* const* d_in, const int* in_sizes, int n_in,
                              void* d_out, int out_size, void* d_ws, size_t ws_size,
                              hipStream_t stream) {
    const float* un    = (const float*)d_in[0];   // [B, 3]
    const float* table = (const float*)d_in[1];   // [128,128,128,8]
    float* out         = (float*)d_out;           // [B, 8]
    int batch = in_sizes[0] / 3;

    size_t need = (size_t)REC_OFF + (size_t)batch * 16;
    if (ws_size < need) {
        int grid = (batch + 255) / 256;
        k_naive<<<grid, 256, 0, stream>>>(un, table, out, batch);
        return;
    }

    unsigned* hist   = (unsigned*)d_ws;
    unsigned* base   = (unsigned*)((char*)d_ws + 512);
    unsigned* cursor = (unsigned*)((char*)d_ws + 1024);
    float4*   rec    = (float4*)((char*)d_ws + REC_OFF);

    hipMemsetAsync(d_ws, 0, 1536, stream);
    k_hist<<<512, 256, 0, stream>>>(un, hist, batch);
    k_scan<<<1, 128, 0, stream>>>(hist, base, cursor);
    int nscat = (batch + CHUNK - 1) / CHUNK;
    k_scatter<<<nscat, 256, 0, stream>>>(un, cursor, rec, batch);
    int nmain = (batch + 255) / 256;
    nmain = ((nmain + 7) / 8) * 8;   // multiple of 8 for the XCD swizzle
    k_main<<<nmain, 256, 0, stream>>>(rec, table, out, batch);
}

// Round 3
// 113.324 us; speedup vs baseline: 1.9164x; 1.3972x over previous
//
#include <hip/hip_runtime.h>

// Trilinear table lookup, spatially sorted + quad-cooperative gather.
//
// unList: [B,3] f32 in [0,1]; table: [128,128,128,8] f32; out: [B,8] f32
//
// Pipeline: hist(x-plane) -> scan -> scatter(sorted records) -> main.
// Main kernel: 4 lanes per point; each (bx,by) corner-pair group is 64 B
// (16 floats: z0-corner ch0-7, z1-corner ch0-7); lane q loads float4 at
// q*16B so the 4 requests coalesce into the same cache line within one
// instruction. z-corners combined via __shfl_xor(2); lanes q<2 store.

#define DIM 128
#define CH 8
#define BINS 128
#define CHUNK 4096
#define PPT 16
#define REC_OFF 4096

__device__ __forceinline__ int key_of(float ux) {
    float sx = fminf(fmaxf(ux, 0.0f), 1.0f) * 127.0f;
    float fx0 = fminf(floorf(sx), 126.0f);
    return (int)fx0;
}

__global__ __launch_bounds__(256) void k_hist(const float* __restrict__ un,
                                              unsigned* __restrict__ hist, int batch) {
    __shared__ unsigned lh[BINS];
    for (int i = threadIdx.x; i < BINS; i += blockDim.x) lh[i] = 0;
    __syncthreads();
    int stride = gridDim.x * blockDim.x;
    for (int i = blockIdx.x * blockDim.x + threadIdx.x; i < batch; i += stride)
        atomicAdd(&lh[key_of(un[3 * i])], 1u);
    __syncthreads();
    for (int i = threadIdx.x; i < BINS; i += blockDim.x)
        if (lh[i]) atomicAdd(&hist[i], lh[i]);
}

__global__ void k_scan(const unsigned* __restrict__ hist,
                       unsigned* __restrict__ base, unsigned* __restrict__ cursor) {
    __shared__ unsigned lh[BINS];
    __shared__ unsigned lb[BINS];
    int t = threadIdx.x;
    if (t < BINS) lh[t] = hist[t];
    __syncthreads();
    if (t == 0) {
        unsigned acc = 0;
        for (int i = 0; i < BINS; ++i) { lb[i] = acc; acc += lh[i]; }
    }
    __syncthreads();
    if (t < BINS) { base[t] = lb[t]; cursor[t] = lb[t]; }
}

__global__ __launch_bounds__(256) void k_scatter(const float* __restrict__ un,
                                                 unsigned* __restrict__ cursor,
                                                 float4* __restrict__ rec, int batch) {
    __shared__ unsigned lh[BINS];
    __shared__ unsigned lbase[BINS];
    int t = threadIdx.x;
    for (int i = t; i < BINS; i += blockDim.x) lh[i] = 0;
    __syncthreads();
    int start = blockIdx.x * CHUNK;
    unsigned kr[PPT];
#pragma unroll
    for (int j = 0; j < PPT; ++j) {
        int i = start + j * 256 + t;
        if (i < batch) {
            int k = key_of(un[3 * i]);
            unsigned r = atomicAdd(&lh[k], 1u);
            kr[j] = (unsigned)k | (r << 8);
        } else kr[j] = 0xFFFFFFFFu;
    }
    __syncthreads();
    for (int i = t; i < BINS; i += blockDim.x)
        lbase[i] = lh[i] ? atomicAdd(&cursor[i], lh[i]) : 0u;
    __syncthreads();
#pragma unroll
    for (int j = 0; j < PPT; ++j) {
        int i = start + j * 256 + t;
        if (i < batch) {
            unsigned k = kr[j] & 0xFFu, r = kr[j] >> 8;
            float ux = un[3 * i], uy = un[3 * i + 1], uz = un[3 * i + 2];
            rec[lbase[k] + r] = make_float4(ux, uy, uz, __uint_as_float((unsigned)i));
        }
    }
}

// Quad-cooperative main kernel: 4 lanes/point, 16 points per wave-pass,
// 64 points per 256-thread block per pass (single pass; grid covers B/64).
__global__ __launch_bounds__(256) void k_main(const float4* __restrict__ rec,
                                              const float* __restrict__ table,
                                              float* __restrict__ out, int batch) {
    // XCD-aware swizzle (gridDim.x % 8 == 0 by launch)
    int per = gridDim.x >> 3;
    int pb = blockIdx.x;
    int lb = (pb & 7) * per + (pb >> 3);

    int t = (int)threadIdx.x;
    int lane = t & 63;
    int wave = t >> 6;
    int p = lane >> 2;        // point within wave-pass: 0..15
    int q = lane & 3;         // quad sub-lane

    int i = lb * 64 + wave * 16 + p;
    if (i >= batch) return;

    float4 r = rec[i];
    unsigned orig = __float_as_uint(r.w);

    const float dmax = 127.0f, imax = 126.0f;
    float sx = fminf(fmaxf(r.x, 0.0f), 1.0f) * dmax;
    float sy = fminf(fmaxf(r.y, 0.0f), 1.0f) * dmax;
    float sz = fminf(fmaxf(r.z, 0.0f), 1.0f) * dmax;
    float fx0 = fminf(fmaxf(floorf(sx), 0.0f), imax);
    float fy0 = fminf(fmaxf(floorf(sy), 0.0f), imax);
    float fz0 = fminf(fmaxf(floorf(sz), 0.0f), imax);
    int x0 = (int)fx0, y0 = (int)fy0, z0 = (int)fz0;
    float fx = sx - fx0, fy = sy - fy0, fz = sz - fz0;

    float wx[2] = {1.0f - fx, fx};
    float wy[2] = {1.0f - fy, fy};
    float wzq = (q & 2) ? fz : (1.0f - fz);   // lane's z-corner weight

    float4 acc = make_float4(0.f, 0.f, 0.f, 0.f);
    // group base: 16 contiguous floats at (x0+bx, y0+by, z0, ch0); lane q
    // loads float4 #q of the 64B span -> same-line coalescing within instr.
#pragma unroll
    for (int bx = 0; bx < 2; ++bx) {
#pragma unroll
        for (int by = 0; by < 2; ++by) {
            const float* pbase = table +
                ((size_t)((x0 + bx) * DIM + (y0 + by)) * DIM + z0) * CH + (q << 2);
            float w = wx[bx] * wy[by] * wzq;
            float4 v = *reinterpret_cast<const float4*>(pbase);
            acc.x += w * v.x;
            acc.y += w * v.y;
            acc.z += w * v.z;
            acc.w += w * v.w;
        }
    }

    // combine z-corners across the quad (q ^ 2 partner)
    acc.x += __shfl_xor(acc.x, 2);
    acc.y += __shfl_xor(acc.y, 2);
    acc.z += __shfl_xor(acc.z, 2);
    acc.w += __shfl_xor(acc.w, 2);

    if (q < 2) {
        *reinterpret_cast<float4*>(out + (size_t)orig * CH + (q << 2)) = acc;
    }
}

// Fallback (no workspace): direct gather.
__global__ __launch_bounds__(256) void k_naive(const float* __restrict__ un,
                                               const float* __restrict__ table,
                                               float* __restrict__ out, int batch) {
    int b = blockIdx.x * blockDim.x + threadIdx.x;
    if (b >= batch) return;
    float ux = un[3 * b], uy = un[3 * b + 1], uz = un[3 * b + 2];
    const float dmax = 127.0f, imax = 126.0f;
    float sx = fminf(fmaxf(ux, 0.0f), 1.0f) * dmax;
    float sy = fminf(fmaxf(uy, 0.0f), 1.0f) * dmax;
    float sz = fminf(fmaxf(uz, 0.0f), 1.0f) * dmax;
    float fx0 = fminf(fmaxf(floorf(sx), 0.0f), imax);
    float fy0 = fminf(fmaxf(floorf(sy), 0.0f), imax);
    float fz0 = fminf(fmaxf(floorf(sz), 0.0f), imax);
    int x0 = (int)fx0, y0 = (int)fy0, z0 = (int)fz0;
    float fx = sx - fx0, fy = sy - fy0, fz = sz - fz0;
    float wx[2] = {1.0f - fx, fx};
    float wy[2] = {1.0f - fy, fy};
    float wz0 = 1.0f - fz, wz1 = fz;
    float acc[CH];
#pragma unroll
    for (int c = 0; c < CH; ++c) acc[c] = 0.0f;
#pragma unroll
    for (int bx = 0; bx < 2; ++bx)
#pragma unroll
        for (int by = 0; by < 2; ++by) {
            const float* p = table + ((size_t)((x0 + bx) * DIM + (y0 + by)) * DIM + z0) * CH;
            float wxy = wx[bx] * wy[by];
            float w0 = wxy * wz0, w1 = wxy * wz1;
            float4 a0 = *reinterpret_cast<const float4*>(p + 0);
            float4 a1 = *reinterpret_cast<const float4*>(p + 4);
            float4 b0 = *reinterpret_cast<const float4*>(p + 8);
            float4 b1 = *reinterpret_cast<const float4*>(p + 12);
            acc[0] += w0 * a0.x + w1 * b0.x;  acc[1] += w0 * a0.y + w1 * b0.y;
            acc[2] += w0 * a0.z + w1 * b0.z;  acc[3] += w0 * a0.w + w1 * b0.w;
            acc[4] += w0 * a1.x + w1 * b1.x;  acc[5] += w0 * a1.y + w1 * b1.y;
            acc[6] += w0 * a1.z + w1 * b1.z;  acc[7] += w0 * a1.w + w1 * b1.w;
        }
    float4* o = reinterpret_cast<float4*>(out + (size_t)b * CH);
    o[0] = make_float4(acc[0], acc[1], acc[2], acc[3]);
    o[1] = make_float4(acc[4], acc[5], acc[6], acc[7]);
}

extern "C" void kernel_launch(void* const* d_in, const int* in_sizes, int n_in,
                              void* d_out, int out_size, void* d_ws, size_t ws_size,
                              hipStream_t stream) {
    const float* un    = (const float*)d_in[0];
    const float* table = (const float*)d_in[1];
    float* out         = (float*)d_out;
    int batch = in_sizes[0] / 3;

    size_t need = (size_t)REC_OFF + (size_t)batch * 16;
    if (ws_size < need) {
        int grid = (batch + 255) / 256;
        k_naive<<<grid, 256, 0, stream>>>(un, table, out, batch);
        return;
    }

    unsigned* hist   = (unsigned*)d_ws;
    unsigned* base   = (unsigned*)((char*)d_ws + 512);
    unsigned* cursor = (unsigned*)((char*)d_ws + 1024);
    float4*   rec    = (float4*)((char*)d_ws + REC_OFF);

    hipMemsetAsync(d_ws, 0, 1536, stream);
    k_hist<<<512, 256, 0, stream>>>(un, hist, batch);
    k_scan<<<1, 128, 0, stream>>>(hist, base, cursor);
    int nscat = (batch + CHUNK - 1) / CHUNK;
    k_scatter<<<nscat, 256, 0, stream>>>(un, cursor, rec, batch);
    // 64 points per block (4 waves x 16 points)
    int nmain = (batch + 63) / 64;
    nmain = ((nmain + 7) / 8) * 8;   // multiple of 8 for XCD swizzle
    k_main<<<nmain, 256, 0, stream>>>(rec, table, out, batch);
}